// Round 7
// baseline (7421.492 us; speedup 1.0000x reference)
//
#include <hip/hip_runtime.h>

#define T_STEPS 4096
#define HDIM 1024

typedef __bf16 bf16x8 __attribute__((ext_vector_type(8)));
typedef float f32x4 __attribute__((ext_vector_type(4)));
typedef _Float16 half2_t __attribute__((ext_vector_type(2)));

__device__ __forceinline__ unsigned short f2bf(float x) {
  unsigned u = __builtin_bit_cast(unsigned, x);
  u += 0x7fffu + ((u >> 16) & 1u);   // RNE
  return (unsigned short)(u >> 16);
}
__device__ __forceinline__ float bf2f(unsigned short b) {
  unsigned u = ((unsigned)b) << 16;
  return __builtin_bit_cast(float, u);
}

// ---------------------------------------------------------------------------
// Kernel 1: build xs_bf16 [2][4096][2048] from res_for / res_back.
// ---------------------------------------------------------------------------
__global__ __launch_bounds__(256) void build_xs(
    const float* __restrict__ rf, const float* __restrict__ rb,
    unsigned short* __restrict__ xs) {
  int idx = blockIdx.x * 256 + threadIdx.x;   // one thread per 4 elems
  int e = idx * 4;
  int f = e & 2047;
  int td = e >> 11;
  int t = td & 4095;
  int d = td >> 12;
  bool lower = f < 1024;
  int f2 = f & 1023;
  int trow;
  if (d == 0) trow = lower ? t : (4095 - t);
  else        trow = lower ? (4095 - t) : t;
  const float* src = (lower ? rf : rb) + trow * 1024 + f2;
  float4 v = *(const float4*)src;
  ushort4 o = make_ushort4(f2bf(v.x), f2bf(v.y), f2bf(v.z), f2bf(v.w));
  *(ushort4*)(xs + e) = o;
}

// ---------------------------------------------------------------------------
// Kernel 2: wxT_bf16 [4096 g][2048 f] = transpose of w[:2048].
// ---------------------------------------------------------------------------
__global__ __launch_bounds__(256) void transpose_wx(
    const float* __restrict__ w, unsigned short* __restrict__ wxT) {
  __shared__ float tile[64][65];
  int bid = blockIdx.x;          // 2048 = 32 (f) * 64 (g)
  int bf_ = bid / 64;
  int bg = bid % 64;
  int f0 = bf_ * 64, g0 = bg * 64;
  int tid = threadIdx.x;
#pragma unroll
  for (int s = 0; s < 16; ++s) {
    int idx = s * 256 + tid;
    int fl = idx >> 6, gl = idx & 63;
    tile[fl][gl] = w[(size_t)(f0 + fl) * 4096 + g0 + gl];
  }
  __syncthreads();
#pragma unroll
  for (int s = 0; s < 16; ++s) {
    int idx = s * 256 + tid;
    int gl = idx >> 6, fl = idx & 63;
    wxT[(size_t)(g0 + gl) * 2048 + f0 + fl] = f2bf(tile[fl][gl]);
  }
}

// ---------------------------------------------------------------------------
// Kernel 3: zx = xs @ wx -> bf16 [8192][4096]. 128x128 tile, BK=32, 4 waves.
// ---------------------------------------------------------------------------
__global__ __launch_bounds__(256) void gemm_zx(
    const unsigned short* __restrict__ xs, const unsigned short* __restrict__ wxT,
    unsigned short* __restrict__ zxo) {
  __shared__ uint4 lds[1024];   // A: bytes [0,8192), B: [8192,16384)
  char* ldsb = (char*)lds;
  int bid = blockIdx.x;
  int by = bid >> 5;
  int bx = bid & 31;
  int tid = threadIdx.x, lane = tid & 63, wid = tid >> 6;
  int wr = wid >> 1, wc = wid & 1;
  const int arow0 = by * 128, bcol0 = bx * 128;

  f32x4 acc[4][4] = {};

  for (int kt = 0; kt < 64; ++kt) {
    int k0 = kt * 32;
#pragma unroll
    for (int s = 0; s < 2; ++s) {
      int c = tid + 256 * s;
      int L = c * 16;
      int P = L ^ (((L >> 6) & 7) << 4);
      int row = c >> 2, ko = (c & 3) * 8;
      uint4 av = *(const uint4*)(xs  + (size_t)(arow0 + row) * 2048 + k0 + ko);
      uint4 bv = *(const uint4*)(wxT + (size_t)(bcol0 + row) * 2048 + k0 + ko);
      *(uint4*)(ldsb + P) = av;
      *(uint4*)(ldsb + 8192 + P) = bv;
    }
    __syncthreads();

    bf16x8 afr[4], bfr[4];
#pragma unroll
    for (int i = 0; i < 4; ++i) {
      int arow = wr * 64 + i * 16 + (lane & 15);
      int L = arow * 64 + (lane >> 4) * 16;
      int P = L ^ ((arow & 7) << 4);
      afr[i] = *(bf16x8*)(ldsb + P);
      int brow = wc * 64 + i * 16 + (lane & 15);
      int L2 = brow * 64 + (lane >> 4) * 16;
      int P2 = L2 ^ ((brow & 7) << 4);
      bfr[i] = *(bf16x8*)(ldsb + 8192 + P2);
    }
#pragma unroll
    for (int mi = 0; mi < 4; ++mi)
#pragma unroll
      for (int ni = 0; ni < 4; ++ni)
        acc[mi][ni] = __builtin_amdgcn_mfma_f32_16x16x32_bf16(
            afr[mi], bfr[ni], acc[mi][ni], 0, 0, 0);
    __syncthreads();
  }

#pragma unroll
  for (int mi = 0; mi < 4; ++mi)
#pragma unroll
    for (int ni = 0; ni < 4; ++ni)
#pragma unroll
      for (int r = 0; r < 4; ++r) {
        int rrow = arow0 + wr * 64 + mi * 16 + (lane >> 4) * 4 + r;
        int col  = bcol0 + wc * 64 + ni * 16 + (lane & 15);
        zxo[(size_t)rrow * 4096 + col] = f2bf(acc[mi][ni][r]);
      }
}

// ---------------------------------------------------------------------------
// Kernel 3.25: pack W_h as f16 pairs.
// ---------------------------------------------------------------------------
__global__ __launch_bounds__(256) void pack_whp(
    const float* __restrict__ w, unsigned* __restrict__ whp) {
  int idx = blockIdx.x * 256 + threadIdx.x;   // [0, 512*4096)
  int gc = idx & 4095;
  int k2 = idx >> 12;
  float w0 = w[(size_t)(2048 + 2 * k2) * 4096 + gc];
  float w1 = w[(size_t)(2048 + 2 * k2 + 1) * 4096 + gc];
  unsigned short a = __builtin_bit_cast(unsigned short, (_Float16)w0);
  unsigned short b = __builtin_bit_cast(unsigned short, (_Float16)w1);
  whp[idx] = ((unsigned)b << 16) | (unsigned)a;
}

// ---------------------------------------------------------------------------
// Kernel 3.5: clear hcom tags (aliases dead xs region; runs after gemm).
// ---------------------------------------------------------------------------
__global__ __launch_bounds__(256) void clear_hcom(uint4* __restrict__ p) {
  p[(size_t)blockIdx.x * 256 + threadIdx.x] = uint4{0, 0, 0, 0};
}

// ---------------------------------------------------------------------------
// Kernel 4: persistent recurrent LSTM. 128 blocks (64/dir) x 1024 threads.
//   - pipelined poll: 4 outstanding same-address loads, vmcnt(3)-paced
//     (detect granularity ~RTT/4; shrinks barrier's max-over-16-waves)
//   - W_h as 32 packed f16-pair u32 / thread; matvec = 32 x v_dot2_f32_f16
//   - single store per step: packed (t+1)<<16 | f16(h) -> hcom (also output
//     carrier; unpack_out converts to f32 d_out afterwards)
// ---------------------------------------------------------------------------
__device__ __forceinline__ float sigm(float x) {
  return 1.0f / (1.0f + __expf(-x));
}
__device__ __forceinline__ float tanh_fast(float x) {
  float e = __expf(-2.0f * x);
  return (1.0f - e) / (1.0f + e);
}

__global__ __launch_bounds__(1024, 4) void lstm_rec(
    const unsigned short* __restrict__ zx,  // [2][4096][4096] bf16
    const unsigned* __restrict__ whp,       // [512][4096] packed f16-pair W_h
    unsigned* __restrict__ hcom) {          // [2][4096][1024] packed tag|f16h
  __shared__ unsigned short hstg[16][64];   // per-wave h f16 stage
  __shared__ float part[2][16][64];         // parity-double-buffered partials

  int bid = blockIdx.x;
  int dir = bid >> 6;
  int bslot = bid & 63;
  int jbase = bslot << 4;                   // 16 j's per block
  int tid = threadIdx.x;
  int wave = tid >> 6;                      // k-slice: wave*64..+63
  int lane = tid & 63;                      // column: jj = lane&15, gate = lane>>4
  int jj = lane & 15, g = lane >> 4;
  int gcol = (g << 10) + jbase + jj;

  // ---- W_h slice into registers: 32 u32 (64 f16), opaque-laundered ----
  unsigned wpk[32];
  {
    const unsigned* wp = whp + (size_t)(wave * 32) * 4096 + gcol;
#pragma unroll
    for (int i = 0; i < 32; ++i) wpk[i] = wp[(size_t)i * 4096];
#pragma unroll
    for (int i = 0; i < 32; ++i)
      asm volatile("v_mov_b32 %0, %0" : "+v"(wpk[i]));
  }

  float c_reg = 0.0f;
  const unsigned short* zrow = zx + (size_t)dir * T_STEPS * 4096;
  unsigned* hcd = hcom + (size_t)dir * T_STEPS * HDIM;
  const unsigned* hp_slice = hcd + wave * 64 + lane;   // + t*HDIM per step

  for (int t = 0; t < T_STEPS; ++t) {
    // wave15 owns the zx contribution (keeps wave0's critical path short)
    float zxv = 0.0f;
    if (wave == 15) zxv = bf2f(zrow[(size_t)t * 4096 + gcol]);

    // pipelined poll of own 64-elem k-slice of h_{t-1}: 4 loads in flight,
    // check oldest via vmcnt(3), merge, reissue. Wave-uniform exit.
    unsigned short hbits = 0;
    if (t > 0) {
      unsigned long long a = (unsigned long long)(hp_slice + (size_t)(t - 1) * HDIM);
      unsigned want = (unsigned)t << 16;    // value monotone: 0 -> want|f16
      unsigned got, p0, p1, p2, p3;
      asm volatile(
        "v_mov_b32 %0, 0\n\t"
        "global_load_dword %2, %6, off sc0 sc1\n\t"
        "global_load_dword %3, %6, off sc0 sc1\n\t"
        "global_load_dword %4, %6, off sc0 sc1\n\t"
        "global_load_dword %5, %6, off sc0 sc1\n\t"
        "1:\n\t"
        "s_waitcnt vmcnt(3)\n\t"
        "v_cmp_le_u32 vcc, %7, %2\n\t"
        "v_cndmask_b32 %0, %0, %2, vcc\n\t"
        "global_load_dword %2, %6, off sc0 sc1\n\t"
        "v_cmp_le_u32 vcc, %7, %0\n\t"
        "s_andn2_b64 vcc, exec, vcc\n\t"
        "s_cbranch_scc0 2f\n\t"
        "s_waitcnt vmcnt(3)\n\t"
        "v_cmp_le_u32 vcc, %7, %3\n\t"
        "v_cndmask_b32 %0, %0, %3, vcc\n\t"
        "global_load_dword %3, %6, off sc0 sc1\n\t"
        "v_cmp_le_u32 vcc, %7, %0\n\t"
        "s_andn2_b64 vcc, exec, vcc\n\t"
        "s_cbranch_scc0 2f\n\t"
        "s_waitcnt vmcnt(3)\n\t"
        "v_cmp_le_u32 vcc, %7, %4\n\t"
        "v_cndmask_b32 %0, %0, %4, vcc\n\t"
        "global_load_dword %4, %6, off sc0 sc1\n\t"
        "v_cmp_le_u32 vcc, %7, %0\n\t"
        "s_andn2_b64 vcc, exec, vcc\n\t"
        "s_cbranch_scc0 2f\n\t"
        "s_waitcnt vmcnt(3)\n\t"
        "v_cmp_le_u32 vcc, %7, %5\n\t"
        "v_cndmask_b32 %0, %0, %5, vcc\n\t"
        "global_load_dword %5, %6, off sc0 sc1\n\t"
        "v_cmp_le_u32 vcc, %7, %0\n\t"
        "s_andn2_b64 vcc, exec, vcc\n\t"
        "s_cbranch_scc1 1b\n\t"
        "2:\n\t"
        "s_waitcnt vmcnt(0)"
        : "=&v"(got), "+v"(a), "=&v"(p0), "=&v"(p1), "=&v"(p2), "=&v"(p3)
        : "v"(a), "v"(want)
        : "vcc", "memory");
      hbits = (unsigned short)got;
    }
    hstg[wave][lane] = hbits;
    asm volatile("s_waitcnt lgkmcnt(0)" ::: "memory");  // wave-local stage done

    // matvec: 32 x dot2 (f16 pairs, f32 accum); broadcast LDS reads
    const unsigned* h2 = (const unsigned*)(&hstg[wave][0]);
    float acc = 0.0f;
#pragma unroll
    for (int i = 0; i < 32; ++i) {
      half2_t hh = __builtin_bit_cast(half2_t, h2[i]);
      half2_t ww = __builtin_bit_cast(half2_t, wpk[i]);
      acc = __builtin_amdgcn_fdot2(ww, hh, acc, false);
    }
    if (wave == 15) acc += zxv;
    part[t & 1][wave][lane] = acc;
    __syncthreads();   // the ONE barrier per step

    // wave0 tail: reduce 16 partials, gates, single packed store
    if (wave == 0) {
      float z = 0.f;
#pragma unroll
      for (int q = 0; q < 16; ++q) z += part[t & 1][q][lane];
      float gz = (g == 2) ? z + 1.0f : z;       // FORGET_BIAS on f gate
      float nl = (g == 1) ? tanh_fast(z) : sigm(gz);
      float iv = __shfl(nl, jj, 64);
      float cv = __shfl(nl, 16 + jj, 64);
      float fv = __shfl(nl, 32 + jj, 64);
      float ov = __shfl(nl, 48 + jj, 64);
      if (lane < 16) {
        float cs = fmaf(fv, c_reg, iv * cv);
        cs = fminf(3.0f, fmaxf(-3.0f, cs));     // CELL_CLIP
        c_reg = cs;
        float h = ov * tanh_fast(cs);
        unsigned short hb = __builtin_bit_cast(unsigned short, (_Float16)h);
        unsigned pk = ((unsigned)(t + 1) << 16) | (unsigned)hb;
        __hip_atomic_store(&hcd[(size_t)t * HDIM + jbase + lane], pk,
                           __ATOMIC_RELAXED, __HIP_MEMORY_SCOPE_AGENT);
      }
    }
    // no trailing barrier: part is parity-double-buffered
  }
}

// ---------------------------------------------------------------------------
// Kernel 5: unpack hcom (tag|f16) -> f32 output.
// ---------------------------------------------------------------------------
__global__ __launch_bounds__(256) void unpack_out(
    const unsigned* __restrict__ hcom, float* __restrict__ out) {
  int i = blockIdx.x * 256 + threadIdx.x;   // one thread per 4 elems
  uint4 v = ((const uint4*)hcom)[i];
  float4 o;
  o.x = (float)__builtin_bit_cast(_Float16, (unsigned short)v.x);
  o.y = (float)__builtin_bit_cast(_Float16, (unsigned short)v.y);
  o.z = (float)__builtin_bit_cast(_Float16, (unsigned short)v.z);
  o.w = (float)__builtin_bit_cast(_Float16, (unsigned short)v.w);
  ((float4*)out)[i] = o;
}

// ---------------------------------------------------------------------------
// launch
// ---------------------------------------------------------------------------
extern "C" void kernel_launch(void* const* d_in, const int* in_sizes, int n_in,
                              void* d_out, int out_size, void* d_ws, size_t ws_size,
                              hipStream_t stream) {
  const float* rf = (const float*)d_in[0];   // res_for_1  [1][4096][1024]
  const float* rb = (const float*)d_in[1];   // res_back_1 [1][4096][1024]
  const float* w  = (const float*)d_in[2];   // w [3072][4096]
  float* out = (float*)d_out;                // [2][4096][1024]

  char* ws = (char*)d_ws;
  unsigned short* zx  = (unsigned short*)ws;                          // [0, 64 MiB)
  unsigned short* xs  = (unsigned short*)(ws + (64u << 20));          // [64, 96 MiB)
  unsigned*      hcom = (unsigned*)(ws + (64u << 20));                // aliases xs (dead after gemm)
  unsigned short* wxT = (unsigned short*)(ws + (96u << 20));          // [96, 112 MiB)
  unsigned*      whp  = (unsigned*)(ws + (96u << 20));                // aliases wxT (dead after gemm)

  build_xs<<<16384, 256, 0, stream>>>(rf, rb, xs);
  transpose_wx<<<2048, 256, 0, stream>>>(w, wxT);
  gemm_zx<<<2048, 256, 0, stream>>>(xs, wxT, zx);
  pack_whp<<<8192, 256, 0, stream>>>(w, whp);           // after gemm: wxT dead
  clear_hcom<<<8192, 256, 0, stream>>>((uint4*)hcom);   // zero tags (32 MiB)
  lstm_rec<<<128, 1024, 0, stream>>>(zx, whp, hcom);
  unpack_out<<<8192, 256, 0, stream>>>(hcom, out);
}

// Round 8
// 6347.166 us; speedup vs baseline: 1.1693x; 1.1693x over previous
//
#include <hip/hip_runtime.h>

#define T_STEPS 4096
#define HDIM 1024

typedef __bf16 bf16x8 __attribute__((ext_vector_type(8)));
typedef float f32x4 __attribute__((ext_vector_type(4)));
typedef _Float16 half2_t __attribute__((ext_vector_type(2)));

__device__ __forceinline__ unsigned short f2bf(float x) {
  unsigned u = __builtin_bit_cast(unsigned, x);
  u += 0x7fffu + ((u >> 16) & 1u);   // RNE
  return (unsigned short)(u >> 16);
}
__device__ __forceinline__ float bf2f(unsigned short b) {
  unsigned u = ((unsigned)b) << 16;
  return __builtin_bit_cast(float, u);
}

// ---------------------------------------------------------------------------
// Kernel 1: build xs_bf16 [2][4096][2048] from res_for / res_back.
// ---------------------------------------------------------------------------
__global__ __launch_bounds__(256) void build_xs(
    const float* __restrict__ rf, const float* __restrict__ rb,
    unsigned short* __restrict__ xs) {
  int idx = blockIdx.x * 256 + threadIdx.x;   // one thread per 4 elems
  int e = idx * 4;
  int f = e & 2047;
  int td = e >> 11;
  int t = td & 4095;
  int d = td >> 12;
  bool lower = f < 1024;
  int f2 = f & 1023;
  int trow;
  if (d == 0) trow = lower ? t : (4095 - t);
  else        trow = lower ? (4095 - t) : t;
  const float* src = (lower ? rf : rb) + trow * 1024 + f2;
  float4 v = *(const float4*)src;
  ushort4 o = make_ushort4(f2bf(v.x), f2bf(v.y), f2bf(v.z), f2bf(v.w));
  *(ushort4*)(xs + e) = o;
}

// ---------------------------------------------------------------------------
// Kernel 2: wxT_bf16 [4096 g][2048 f] = transpose of w[:2048].
// ---------------------------------------------------------------------------
__global__ __launch_bounds__(256) void transpose_wx(
    const float* __restrict__ w, unsigned short* __restrict__ wxT) {
  __shared__ float tile[64][65];
  int bid = blockIdx.x;          // 2048 = 32 (f) * 64 (g)
  int bf_ = bid / 64;
  int bg = bid % 64;
  int f0 = bf_ * 64, g0 = bg * 64;
  int tid = threadIdx.x;
#pragma unroll
  for (int s = 0; s < 16; ++s) {
    int idx = s * 256 + tid;
    int fl = idx >> 6, gl = idx & 63;
    tile[fl][gl] = w[(size_t)(f0 + fl) * 4096 + g0 + gl];
  }
  __syncthreads();
#pragma unroll
  for (int s = 0; s < 16; ++s) {
    int idx = s * 256 + tid;
    int gl = idx >> 6, fl = idx & 63;
    wxT[(size_t)(g0 + gl) * 2048 + f0 + fl] = f2bf(tile[fl][gl]);
  }
}

// ---------------------------------------------------------------------------
// Kernel 3: zx = xs @ wx -> bf16 [8192][4096]. 128x128 tile, BK=32, 4 waves.
// ---------------------------------------------------------------------------
__global__ __launch_bounds__(256) void gemm_zx(
    const unsigned short* __restrict__ xs, const unsigned short* __restrict__ wxT,
    unsigned short* __restrict__ zxo) {
  __shared__ uint4 lds[1024];   // A: bytes [0,8192), B: [8192,16384)
  char* ldsb = (char*)lds;
  int bid = blockIdx.x;
  int by = bid >> 5;
  int bx = bid & 31;
  int tid = threadIdx.x, lane = tid & 63, wid = tid >> 6;
  int wr = wid >> 1, wc = wid & 1;
  const int arow0 = by * 128, bcol0 = bx * 128;

  f32x4 acc[4][4] = {};

  for (int kt = 0; kt < 64; ++kt) {
    int k0 = kt * 32;
#pragma unroll
    for (int s = 0; s < 2; ++s) {
      int c = tid + 256 * s;
      int L = c * 16;
      int P = L ^ (((L >> 6) & 7) << 4);
      int row = c >> 2, ko = (c & 3) * 8;
      uint4 av = *(const uint4*)(xs  + (size_t)(arow0 + row) * 2048 + k0 + ko);
      uint4 bv = *(const uint4*)(wxT + (size_t)(bcol0 + row) * 2048 + k0 + ko);
      *(uint4*)(ldsb + P) = av;
      *(uint4*)(ldsb + 8192 + P) = bv;
    }
    __syncthreads();

    bf16x8 afr[4], bfr[4];
#pragma unroll
    for (int i = 0; i < 4; ++i) {
      int arow = wr * 64 + i * 16 + (lane & 15);
      int L = arow * 64 + (lane >> 4) * 16;
      int P = L ^ ((arow & 7) << 4);
      afr[i] = *(bf16x8*)(ldsb + P);
      int brow = wc * 64 + i * 16 + (lane & 15);
      int L2 = brow * 64 + (lane >> 4) * 16;
      int P2 = L2 ^ ((brow & 7) << 4);
      bfr[i] = *(bf16x8*)(ldsb + 8192 + P2);
    }
#pragma unroll
    for (int mi = 0; mi < 4; ++mi)
#pragma unroll
      for (int ni = 0; ni < 4; ++ni)
        acc[mi][ni] = __builtin_amdgcn_mfma_f32_16x16x32_bf16(
            afr[mi], bfr[ni], acc[mi][ni], 0, 0, 0);
    __syncthreads();
  }

#pragma unroll
  for (int mi = 0; mi < 4; ++mi)
#pragma unroll
    for (int ni = 0; ni < 4; ++ni)
#pragma unroll
      for (int r = 0; r < 4; ++r) {
        int rrow = arow0 + wr * 64 + mi * 16 + (lane >> 4) * 4 + r;
        int col  = bcol0 + wc * 64 + ni * 16 + (lane & 15);
        zxo[(size_t)rrow * 4096 + col] = f2bf(acc[mi][ni][r]);
      }
}

// ---------------------------------------------------------------------------
// Kernel 3.25: pack W_h as f16 pairs.
// ---------------------------------------------------------------------------
__global__ __launch_bounds__(256) void pack_whp(
    const float* __restrict__ w, unsigned* __restrict__ whp) {
  int idx = blockIdx.x * 256 + threadIdx.x;   // [0, 512*4096)
  int gc = idx & 4095;
  int k2 = idx >> 12;
  float w0 = w[(size_t)(2048 + 2 * k2) * 4096 + gc];
  float w1 = w[(size_t)(2048 + 2 * k2 + 1) * 4096 + gc];
  unsigned short a = __builtin_bit_cast(unsigned short, (_Float16)w0);
  unsigned short b = __builtin_bit_cast(unsigned short, (_Float16)w1);
  whp[idx] = ((unsigned)b << 16) | (unsigned)a;
}

// ---------------------------------------------------------------------------
// Kernel 3.5: clear hcom tags (aliases dead xs region; runs after gemm).
// ---------------------------------------------------------------------------
__global__ __launch_bounds__(256) void clear_hcom(uint4* __restrict__ p) {
  p[(size_t)blockIdx.x * 256 + threadIdx.x] = uint4{0, 0, 0, 0};
}

// ---------------------------------------------------------------------------
// Kernel 4: persistent recurrent LSTM. 128 blocks (64/dir) x 1024 threads.
//   - simple dependent-load poll (R6 — R7's 4-deep pipelined poll congested
//     the IF/L3 and regressed; lighter polling wins)
//   - W_h as 32 packed f16-pair u32 / thread; matvec = 32 x v_dot2_f32_f16
//     with h read from LDS as 8 uniform ds_read_b128 (broadcast), 4 accums
//   - single store per step: packed (t+1)<<16 | f16(h) -> hcom (also output
//     carrier; unpack_out converts to f32 d_out afterwards)
// ---------------------------------------------------------------------------
__device__ __forceinline__ float sigm(float x) {
  return 1.0f / (1.0f + __expf(-x));
}
__device__ __forceinline__ float tanh_fast(float x) {
  float e = __expf(-2.0f * x);
  return (1.0f - e) / (1.0f + e);
}

__global__ __launch_bounds__(1024, 4) void lstm_rec(
    const unsigned short* __restrict__ zx,  // [2][4096][4096] bf16
    const unsigned* __restrict__ whp,       // [512][4096] packed f16-pair W_h
    unsigned* __restrict__ hcom) {          // [2][4096][1024] packed tag|f16h
  __shared__ unsigned short hstg[16][64];   // per-wave h f16 stage (128B rows)
  __shared__ float part[2][16][64];         // parity-double-buffered partials

  int bid = blockIdx.x;
  int dir = bid >> 6;
  int bslot = bid & 63;
  int jbase = bslot << 4;                   // 16 j's per block
  int tid = threadIdx.x;
  int wave = tid >> 6;                      // k-slice: wave*64..+63
  int lane = tid & 63;                      // column: jj = lane&15, gate = lane>>4
  int jj = lane & 15, g = lane >> 4;
  int gcol = (g << 10) + jbase + jj;

  // ---- W_h slice into registers: 32 u32 (64 f16), opaque-laundered ----
  unsigned wpk[32];
  {
    const unsigned* wp = whp + (size_t)(wave * 32) * 4096 + gcol;
#pragma unroll
    for (int i = 0; i < 32; ++i) wpk[i] = wp[(size_t)i * 4096];
#pragma unroll
    for (int i = 0; i < 32; ++i)
      asm volatile("v_mov_b32 %0, %0" : "+v"(wpk[i]));
  }

  float c_reg = 0.0f;
  const unsigned short* zrow = zx + (size_t)dir * T_STEPS * 4096;
  unsigned* hcd = hcom + (size_t)dir * T_STEPS * HDIM;
  const unsigned* hp_slice = hcd + wave * 64 + lane;   // + t*HDIM per step

  for (int t = 0; t < T_STEPS; ++t) {
    // wave15 owns the zx contribution (keeps wave0's critical path short)
    float zxv = 0.0f;
    if (wave == 15) zxv = bf2f(zrow[(size_t)t * 4096 + gcol]);

    // simple poll of own 64-elem k-slice of h_{t-1}; the poll IS the h load.
    // tag monotone {0, t<<16|f16}, so unsigned < works.
    unsigned short hbits = 0;
    if (t > 0) {
      const unsigned* hp = hp_slice + (size_t)(t - 1) * HDIM;
      unsigned want = (unsigned)t << 16;
      unsigned v;
      do {
        v = __hip_atomic_load(hp, __ATOMIC_RELAXED, __HIP_MEMORY_SCOPE_AGENT);
      } while (v < want);
      hbits = (unsigned short)v;            // f16 payload
    }
    hstg[wave][lane] = hbits;
    asm volatile("s_waitcnt lgkmcnt(0)" ::: "memory");  // wave-local stage done

    // matvec: h via 8 uniform ds_read_b128 (broadcast, conflict-free);
    // 32 x v_dot2_f32_f16 split over 4 accumulators (dep-chain depth 8).
    const uint4* h4p = (const uint4*)(&hstg[wave][0]);
    float ac0 = 0.f, ac1 = 0.f, ac2 = 0.f, ac3 = 0.f;
#pragma unroll
    for (int i = 0; i < 8; ++i) {
      uint4 hv = h4p[i];
      ac0 = __builtin_amdgcn_fdot2(__builtin_bit_cast(half2_t, wpk[4 * i + 0]),
                                   __builtin_bit_cast(half2_t, hv.x), ac0, false);
      ac1 = __builtin_amdgcn_fdot2(__builtin_bit_cast(half2_t, wpk[4 * i + 1]),
                                   __builtin_bit_cast(half2_t, hv.y), ac1, false);
      ac2 = __builtin_amdgcn_fdot2(__builtin_bit_cast(half2_t, wpk[4 * i + 2]),
                                   __builtin_bit_cast(half2_t, hv.z), ac2, false);
      ac3 = __builtin_amdgcn_fdot2(__builtin_bit_cast(half2_t, wpk[4 * i + 3]),
                                   __builtin_bit_cast(half2_t, hv.w), ac3, false);
    }
    float acc = (ac0 + ac1) + (ac2 + ac3);
    if (wave == 15) acc += zxv;
    part[t & 1][wave][lane] = acc;
    __syncthreads();   // the ONE barrier per step

    // wave0 tail: reduce 16 partials, gates, single packed store
    if (wave == 0) {
      float z = 0.f;
#pragma unroll
      for (int q = 0; q < 16; ++q) z += part[t & 1][q][lane];
      float gz = (g == 2) ? z + 1.0f : z;       // FORGET_BIAS on f gate
      float nl = (g == 1) ? tanh_fast(z) : sigm(gz);
      float iv = __shfl(nl, jj, 64);
      float cv = __shfl(nl, 16 + jj, 64);
      float fv = __shfl(nl, 32 + jj, 64);
      float ov = __shfl(nl, 48 + jj, 64);
      if (lane < 16) {
        float cs = fmaf(fv, c_reg, iv * cv);
        cs = fminf(3.0f, fmaxf(-3.0f, cs));     // CELL_CLIP
        c_reg = cs;
        float h = ov * tanh_fast(cs);
        unsigned short hb = __builtin_bit_cast(unsigned short, (_Float16)h);
        unsigned pk = ((unsigned)(t + 1) << 16) | (unsigned)hb;
        __hip_atomic_store(&hcd[(size_t)t * HDIM + jbase + lane], pk,
                           __ATOMIC_RELAXED, __HIP_MEMORY_SCOPE_AGENT);
      }
    }
    // no trailing barrier: part is parity-double-buffered
  }
}

// ---------------------------------------------------------------------------
// Kernel 5: unpack hcom (tag|f16) -> f32 output.
// ---------------------------------------------------------------------------
__global__ __launch_bounds__(256) void unpack_out(
    const unsigned* __restrict__ hcom, float* __restrict__ out) {
  int i = blockIdx.x * 256 + threadIdx.x;   // one thread per 4 elems
  uint4 v = ((const uint4*)hcom)[i];
  float4 o;
  o.x = (float)__builtin_bit_cast(_Float16, (unsigned short)v.x);
  o.y = (float)__builtin_bit_cast(_Float16, (unsigned short)v.y);
  o.z = (float)__builtin_bit_cast(_Float16, (unsigned short)v.z);
  o.w = (float)__builtin_bit_cast(_Float16, (unsigned short)v.w);
  ((float4*)out)[i] = o;
}

// ---------------------------------------------------------------------------
// launch
// ---------------------------------------------------------------------------
extern "C" void kernel_launch(void* const* d_in, const int* in_sizes, int n_in,
                              void* d_out, int out_size, void* d_ws, size_t ws_size,
                              hipStream_t stream) {
  const float* rf = (const float*)d_in[0];   // res_for_1  [1][4096][1024]
  const float* rb = (const float*)d_in[1];   // res_back_1 [1][4096][1024]
  const float* w  = (const float*)d_in[2];   // w [3072][4096]
  float* out = (float*)d_out;                // [2][4096][1024]

  char* ws = (char*)d_ws;
  unsigned short* zx  = (unsigned short*)ws;                          // [0, 64 MiB)
  unsigned short* xs  = (unsigned short*)(ws + (64u << 20));          // [64, 96 MiB)
  unsigned*      hcom = (unsigned*)(ws + (64u << 20));                // aliases xs (dead after gemm)
  unsigned short* wxT = (unsigned short*)(ws + (96u << 20));          // [96, 112 MiB)
  unsigned*      whp  = (unsigned*)(ws + (96u << 20));                // aliases wxT (dead after gemm)

  build_xs<<<16384, 256, 0, stream>>>(rf, rb, xs);
  transpose_wx<<<2048, 256, 0, stream>>>(w, wxT);
  gemm_zx<<<2048, 256, 0, stream>>>(xs, wxT, zx);
  pack_whp<<<8192, 256, 0, stream>>>(w, whp);           // after gemm: wxT dead
  clear_hcom<<<8192, 256, 0, stream>>>((uint4*)hcom);   // zero tags (32 MiB)
  lstm_rec<<<128, 1024, 0, stream>>>(zx, whp, hcom);
  unpack_out<<<8192, 256, 0, stream>>>(hcom, out);
}